// Round 13
// baseline (126.339 us; speedup 1.0000x reference)
//
#include <hip/hip_runtime.h>
#include <math.h>

#define B_   8
#define CIN  256
#define L_   1024
#define NH_  8
#define DH_  32

typedef __attribute__((ext_vector_type(8))) short short8;
typedef __attribute__((ext_vector_type(4))) short short4v;
typedef __attribute__((ext_vector_type(4))) float f32x4;
typedef __attribute__((ext_vector_type(4))) unsigned int uint4v;
typedef __attribute__((ext_vector_type(2))) unsigned int uint2v;

__device__ inline short f2bf_hu(float f) {       // bf16 half-up, 2 ops
    union { float f; unsigned u; } v; v.f = f;
    return (short)((v.u + 0x8000u) >> 16);
}
// pack bf16(a) | bf16(b)<<16 : 2 adds + 1 v_perm
__device__ inline unsigned pkbf2(float a, float b) {
    union { float f; unsigned u; } x, y; x.f = a; y.f = b;
    return __builtin_amdgcn_perm(y.u + 0x8000u, x.u + 0x8000u, 0x07060302u);
}

// ---------------------------------------------------------------------------
// QKV GEMM, fused transpose+cast of x (r7 core + r8 split epilogue).
// Q,K -> qkT[b][l][512]; V -> vT[b][h][dv][l] (transposed, for attn B-frags).
// Tile 64(l) x 128(o): blockIdx.y 0..3 = Q/K, 4..5 = V. Grid 768 = 3/CU.
// ---------------------------------------------------------------------------
__global__ __launch_bounds__(256) void qkv_gemm(
    const float* __restrict__ x, const float* __restrict__ w,
    const float* __restrict__ bias, short* __restrict__ qkT,
    short* __restrict__ vT)
{
    __shared__ short Xs[64][40];
    __shared__ short Wt[128][40];
    const int t = threadIdx.x, lane = t & 63, wv = t >> 6;
    const int n = lane & 15, quad = lane >> 4;
    const int b = blockIdx.z, o0 = blockIdx.y * 128, l0 = blockIdx.x * 64;

    float bias_r[8];
    #pragma unroll
    for (int nf = 0; nf < 8; nf++) bias_r[nf] = bias[o0 + nf * 16 + n];

    f32x4 acc[8];
    #pragma unroll
    for (int nf = 0; nf < 8; nf++) acc[nf] = (f32x4){0.f, 0.f, 0.f, 0.f};

    const int cS = t >> 3, lsS = (t & 7) * 8;       // X stage roles

    for (int c0 = 0; c0 < CIN; c0 += 32) {
        {   // X stage: 32c x 64l fp32, coalesced along l; swizzled transpose
            const float* xp = &x[(((size_t)b * CIN + c0 + cS) << 10) + l0 + lsS];
            const float4 xa = *(const float4*)xp;
            const float4 xb = *(const float4*)(xp + 4);
            const float vals[8] = {xa.x, xa.y, xa.z, xa.w, xb.x, xb.y, xb.z, xb.w};
            #pragma unroll
            for (int k = 0; k < 8; k++) {
                const int l = lsS + k;
                const int col = (((cS >> 3) ^ (l & 3)) << 3) | (cS & 7);
                Xs[l][col] = f2bf_hu(vals[k]);
            }
        }
        {   // W tile: 128x32, fp32 -> bf16 packed, b128 writes
            const int o = t >> 1, cs = (t & 1) * 16;
            const float* wp = &w[(size_t)(o0 + o) * CIN + c0 + cs];
            const float4 w0 = *(const float4*)(wp);
            const float4 w1 = *(const float4*)(wp + 4);
            const float4 w2 = *(const float4*)(wp + 8);
            const float4 w3 = *(const float4*)(wp + 12);
            uint4v pa = { pkbf2(w0.x, w0.y), pkbf2(w0.z, w0.w),
                          pkbf2(w1.x, w1.y), pkbf2(w1.z, w1.w) };
            uint4v pb = { pkbf2(w2.x, w2.y), pkbf2(w2.z, w2.w),
                          pkbf2(w3.x, w3.y), pkbf2(w3.z, w3.w) };
            *(uint4v*)&Wt[o][cs]     = pa;
            *(uint4v*)&Wt[o][cs + 8] = pb;
        }
        __syncthreads();

        const int arow = wv * 16 + n;
        const short8 af = *(const short8*)&Xs[arow][(quad ^ (arow & 3)) * 8];
        #pragma unroll
        for (int nf = 0; nf < 8; nf++) {
            const short8 bf = *(const short8*)&Wt[nf * 16 + n][quad * 8];
            acc[nf] = __builtin_amdgcn_mfma_f32_16x16x32_bf16(af, bf, acc[nf], 0, 0, 0);
        }
        __syncthreads();
    }

    if (o0 < 512) {      // Q,K -> qkT [b][l][512]
        #pragma unroll
        for (int reg = 0; reg < 4; reg++) {
            const size_t l = l0 + wv * 16 + quad * 4 + reg;
            short* row = qkT + ((((size_t)b << 10) + l) << 9) + o0 + n;
            #pragma unroll
            for (int nf = 0; nf < 8; nf++)
                row[nf * 16] = f2bf_hu(acc[nf][reg] + bias_r[nf]);
        }
    } else {             // V -> vT [b][ov=h*32+dv][l]
        #pragma unroll
        for (int reg = 0; reg < 4; reg++) {
            const size_t l = l0 + wv * 16 + quad * 4 + reg;
            #pragma unroll
            for (int nf = 0; nf < 8; nf++) {
                const int ov = o0 - 512 + nf * 16 + n;   // 0..255
                vT[(((size_t)b << 8) + ov << 10) + l] =
                    f2bf_hu(acc[nf][reg] + bias_r[nf]);
            }
        }
    }
}

// ---------------------------------------------------------------------------
// Proj GEMM (validated, unchanged).
// ---------------------------------------------------------------------------
__global__ __launch_bounds__(256) void proj_gemm(
    const short* __restrict__ aT, const float* __restrict__ w,
    const float* __restrict__ bias, const float* __restrict__ resid,
    float* __restrict__ out)
{
    __shared__ short Xs[64][40];
    __shared__ short Wt[64][40];
    const int t = threadIdx.x, lane = t & 63, wv = t >> 6;
    const int n = lane & 15, quad = lane >> 4;
    const int b = blockIdx.z, o0 = blockIdx.y * 64, l0 = blockIdx.x * 64;

    float bias_r[4];
    #pragma unroll
    for (int reg = 0; reg < 4; reg++) bias_r[reg] = bias[o0 + wv * 16 + quad * 4 + reg];

    f32x4 acc[4];
    #pragma unroll
    for (int nf = 0; nf < 4; nf++) acc[nf] = (f32x4){0.f, 0.f, 0.f, 0.f};

    for (int c0 = 0; c0 < CIN; c0 += 32) {
        {   // aT tile 64x32 bf16
            const int l = t >> 2, cs = (t & 3) * 8;
            *(uint4v*)&Xs[l][cs] =
                *(const uint4v*)&aT[(((size_t)b << 10) + l0 + l) * CIN + c0 + cs];
        }
        {   // W tile 64x32, 8 floats per thread
            const int o = t >> 2, cs = (t & 3) * 8;
            const float* wp = &w[(size_t)(o0 + o) * CIN + c0 + cs];
            const float4 a4 = *(const float4*)(wp);
            const float4 b4 = *(const float4*)(wp + 4);
            uint4v pw = { pkbf2(a4.x, a4.y), pkbf2(a4.z, a4.w),
                          pkbf2(b4.x, b4.y), pkbf2(b4.z, b4.w) };
            *(uint4v*)&Wt[o][cs] = pw;
        }
        __syncthreads();

        const short8 af = *(const short8*)&Wt[wv * 16 + n][quad * 8];
        #pragma unroll
        for (int nf = 0; nf < 4; nf++) {
            const short8 bf = *(const short8*)&Xs[nf * 16 + n][quad * 8];
            acc[nf] = __builtin_amdgcn_mfma_f32_16x16x32_bf16(af, bf, acc[nf], 0, 0, 0);
        }
        __syncthreads();
    }

    #pragma unroll
    for (int reg = 0; reg < 4; reg++) {
        const int o = o0 + wv * 16 + quad * 4 + reg;
        #pragma unroll
        for (int nf = 0; nf < 4; nf++) {
            const size_t off = (((size_t)b * CIN + o) << 10) + l0 + nf * 16 + n;
            out[off] = acc[nf][reg] + bias_r[reg] + resid[off];
        }
    }
}

// ---------------------------------------------------------------------------
// Flash attention v7: Q-tile 128 (2 m-frags/wave, r12), ALL K/V operands
// direct from global (K from qkT [l][512], V from vT [dv][l]) with XCD
// swizzle keeping them L2-resident -> ZERO __syncthreads in the K-loop.
// Only LDS use: wave-private Ss (P round-trip) + epilogue. Even/odd unroll,
// bumped pointers, exp2 intrinsic, register ones-column denominator.
// Grid 512 1D (2 blocks/CU).
// ---------------------------------------------------------------------------
__global__ __launch_bounds__(256) void attn_mfma(
    const short* __restrict__ qkT, const short* __restrict__ vT,
    short* __restrict__ attnoT)
{
    __shared__ __align__(16) char umem[128 * 88 * 2];
    short (*Ss)[88] = (short(*)[88])umem;          // [i][j] bf16 P (wave-private rows)
    float (*OtT)[38] = (float(*)[38])umem;         // [i][dv] fp32 epilogue

    const int t = threadIdx.x, lane = t & 63, wv = t >> 6;
    const int n = lane & 15, quad = lane >> 4;
    const int id = blockIdx.x;
    const int bh = id & 63;                        // same-(b,h) -> same XCD
    const int b = bh >> 3, h = bh & 7;
    const int i0 = (id >> 6) * 128;

    const short* qbase = qkT + ((size_t)b << 19) + h * DH_;
    const short* kbase = qbase + 256;
    const short* vtb   = vT + ((size_t)((b << 3) + h) << 15);   // [dv][l], row 1024

    // Q A-frags (2 m-frags per wave) direct from global
    short8 qa[2];
    #pragma unroll
    for (int a = 0; a < 2; a++)
        qa[a] = *(const short8*)&qbase[(size_t)(i0 + wv * 32 + a * 16 + n) * 512 + quad * 8];

    short8 vf2;   // ones-column B-frag (denominator)
    {
        const short one = (n == 0) ? (short)0x3F80 : (short)0;
        #pragma unroll
        for (int u = 0; u < 8; u++) vf2[u] = one;
    }

    f32x4 o_acc[2][3];
    #pragma unroll
    for (int a = 0; a < 2; a++)
        #pragma unroll
        for (int nf = 0; nf < 3; nf++) o_acc[a][nf] = (f32x4){0.f, 0.f, 0.f, 0.f};

    const float K1 = 0.25503510f;    // (1/sqrt(32)) * log2(e)
    const float K2 = 11.54156036f;   // 8 * log2(e)
    const int KSTRIDE = 64 * 512;    // qkT shorts per j-tile
    const int VSTRIDE = 64;          // vT shorts per j-tile (row-dir is dv)

    // ---- persistent bumped pointers ----
    const short* kp0 = kbase + (size_t)n * 512 + quad * 8;
    const short* kp1 = kp0 + 16 * 512;
    const short* kp2 = kp0 + 32 * 512;
    const short* kp3 = kp0 + 48 * 512;
    const short* vp00 = vtb + ((size_t)n) * 1024 + quad * 8;          // kk=0, nf=0
    const short* vp01 = vp00 + 16 * 1024;                             // kk=0, nf=1
    const short* vp10 = vp00 + 32;                                    // kk=1, nf=0
    const short* vp11 = vp01 + 32;                                    // kk=1, nf=1

    // ---- LDS offsets ----
    short* const ssw  = &Ss[wv * 32 + n][quad * 4];        // + a*16*88 + f*16
    const short* const ssr = &Ss[wv * 32 + n][quad * 8];   // + a*16*88 + kk*32

    short8 kfA[4], vfA[2][2], kfB[4], vfB[2][2];

    auto loadKV = [&](short8* kf, short8 vf[2][2]) {
        kf[0] = *(const short8*)kp0; kp0 += KSTRIDE;
        kf[1] = *(const short8*)kp1; kp1 += KSTRIDE;
        kf[2] = *(const short8*)kp2; kp2 += KSTRIDE;
        kf[3] = *(const short8*)kp3; kp3 += KSTRIDE;
        vf[0][0] = *(const short8*)vp00; vp00 += VSTRIDE;
        vf[0][1] = *(const short8*)vp01; vp01 += VSTRIDE;
        vf[1][0] = *(const short8*)vp10; vp10 += VSTRIDE;
        vf[1][1] = *(const short8*)vp11; vp11 += VSTRIDE;
    };
    // one j-tile: 2 m-frags share kf/vf; wave-private Ss round-trip, no barrier
    auto tile = [&](const short8* kf, const short8 vf[2][2]) {
        #pragma unroll
        for (int f = 0; f < 4; f++) {
            #pragma unroll
            for (int a = 0; a < 2; a++) {
                f32x4 z = {0.f, 0.f, 0.f, 0.f};
                const f32x4 sv = __builtin_amdgcn_mfma_f32_16x16x32_bf16(kf[f], qa[a], z, 0, 0, 0);
                const float p0 = __builtin_amdgcn_exp2f(fmaf(sv[0], K1, -K2));
                const float p1 = __builtin_amdgcn_exp2f(fmaf(sv[1], K1, -K2));
                const float p2 = __builtin_amdgcn_exp2f(fmaf(sv[2], K1, -K2));
                const float p3 = __builtin_amdgcn_exp2f(fmaf(sv[3], K1, -K2));
                uint2v pk = { pkbf2(p0, p1), pkbf2(p2, p3) };
                *(uint2v*)(ssw + a * 16 * 88 + f * 16) = pk;
            }
        }
        #pragma unroll
        for (int kk = 0; kk < 2; kk++) {
            short8 pf[2];
            #pragma unroll
            for (int a = 0; a < 2; a++)
                pf[a] = *(const short8*)(ssr + a * 16 * 88 + kk * 32);
            #pragma unroll
            for (int nf = 0; nf < 2; nf++)
                #pragma unroll
                for (int a = 0; a < 2; a++)
                    o_acc[a][nf] = __builtin_amdgcn_mfma_f32_16x16x32_bf16(pf[a], vf[kk][nf], o_acc[a][nf], 0, 0, 0);
            #pragma unroll
            for (int a = 0; a < 2; a++)
                o_acc[a][2] = __builtin_amdgcn_mfma_f32_16x16x32_bf16(pf[a], vf2, o_acc[a][2], 0, 0, 0);
        }
    };

    // ---- zero-barrier K-loop, even/odd unrolled, prefetch depth 1 ----
    loadKV(kfA, vfA);                        // tile 0
    for (int itp = 0; itp < 8; itp++) {
        loadKV(kfB, vfB);                    // tile 2*itp+1
        tile(kfA, vfA);
        if (itp < 7) loadKV(kfA, vfA);       // tile 2*itp+2
        tile(kfB, vfB);
    }

    __syncthreads();   // all PV reads of Ss done before OtT overwrites umem
    #pragma unroll
    for (int a = 0; a < 2; a++)
        #pragma unroll
        for (int r = 0; r < 4; r++) {
            const float lv  = __shfl(o_acc[a][2][r], lane & 48, 64);
            const float inv = 1.f / lv;
            const int il = wv * 32 + a * 16 + quad * 4 + r;
            OtT[il][n]      = o_acc[a][0][r] * inv;
            OtT[il][16 + n] = o_acc[a][1][r] * inv;
        }
    __syncthreads();
    short* ob = attnoT + (((size_t)b << 10) + i0) * CIN + h * DH_;
    #pragma unroll
    for (int r = 0; r < 4; r++) {
        const int idx = t + r * 256;
        const int l = idx >> 3, cs = (idx & 7) * 4;
        uint2v pv;
        pv.x = pkbf2(OtT[l][cs],     OtT[l][cs + 1]);
        pv.y = pkbf2(OtT[l][cs + 2], OtT[l][cs + 3]);
        *(uint2v*)&ob[(size_t)l * CIN + cs] = pv;
    }
}

// ---------------------------------------------------------------------------
extern "C" void kernel_launch(void* const* d_in, const int* in_sizes, int n_in,
                              void* d_out, int out_size, void* d_ws, size_t ws_size,
                              hipStream_t stream) {
    const float* x      = (const float*)d_in[0];
    const float* w_qkv  = (const float*)d_in[1];
    const float* b_qkv  = (const float*)d_in[2];
    const float* w_proj = (const float*)d_in[3];
    const float* b_proj = (const float*)d_in[4];
    float* out = (float*)d_out;

    short* qkT    = (short*)d_ws;                          // 8 MB  [b][l][512]
    short* vT     = qkT + (size_t)B_ * L_ * 512;           // 4 MB  [b][h*32+dv][l]
    short* attnoT = vT  + (size_t)B_ * CIN * L_;           // 4 MB  [b][l][256]

    qkv_gemm<<<dim3(16, 6, B_), 256, 0, stream>>>(x, w_qkv, b_qkv, qkT, vT);
    attn_mfma<<<dim3(512), 256, 0, stream>>>(qkT, vT, attnoT);
    proj_gemm<<<dim3(16, 4, B_), 256, 0, stream>>>(attnoT, w_proj, b_proj, x, out);
}

// Round 14
// 118.825 us; speedup vs baseline: 1.0632x; 1.0632x over previous
//
#include <hip/hip_runtime.h>
#include <math.h>

#define B_   8
#define CIN  256
#define L_   1024
#define NH_  8
#define DH_  32

typedef __attribute__((ext_vector_type(8))) short short8;
typedef __attribute__((ext_vector_type(4))) short short4v;
typedef __attribute__((ext_vector_type(4))) float f32x4;
typedef __attribute__((ext_vector_type(4))) unsigned int uint4v;
typedef __attribute__((ext_vector_type(2))) unsigned int uint2v;

__device__ inline short f2bf_hu(float f) {       // bf16 half-up, 2 ops
    union { float f; unsigned u; } v; v.f = f;
    return (short)((v.u + 0x8000u) >> 16);
}
// pack bf16(a) | bf16(b)<<16 : 2 adds + 1 v_perm
__device__ inline unsigned pkbf2(float a, float b) {
    union { float f; unsigned u; } x, y; x.f = a; y.f = b;
    return __builtin_amdgcn_perm(y.u + 0x8000u, x.u + 0x8000u, 0x07060302u);
}

// ---------------------------------------------------------------------------
// QKV GEMM v2: tile 128(l) x 96(o), grid 8x8x8 = 512 = 2/CU exact.
// X staged from fp32 x[c][l] via 4c x 4l register-block transpose ->
// b64 swizzled LDS writes (~2-way banks vs 16-way scalar writes before).
// Read swizzle identical to r12: col = (quad ^ (l&3))*8.
// ---------------------------------------------------------------------------
__global__ __launch_bounds__(256) void qkv_gemm(
    const float* __restrict__ x, const float* __restrict__ w,
    const float* __restrict__ bias, short* __restrict__ qkvT)
{
    __shared__ short Xs[128][40];
    __shared__ short Wt[96][40];
    const int t = threadIdx.x, lane = t & 63, wv = t >> 6;
    const int n = lane & 15, quad = lane >> 4;
    const int b = blockIdx.z, o0 = blockIdx.y * 96, l0 = blockIdx.x * 128;

    float bias_r[6];
    #pragma unroll
    for (int nf = 0; nf < 6; nf++) bias_r[nf] = bias[o0 + nf * 16 + n];

    f32x4 acc[2][6];
    #pragma unroll
    for (int a = 0; a < 2; a++)
        #pragma unroll
        for (int nf = 0; nf < 6; nf++) acc[a][nf] = (f32x4){0.f, 0.f, 0.f, 0.f};

    const int cS4 = (t & 7) * 4;     // c base (0..28)
    const int lg4 = (t >> 3) * 4;    // l base (0..124)

    for (int c0 = 0; c0 < CIN; c0 += 32) {
        {   // X stage: 4 c-rows x 4 l, b64 swizzled transpose writes
            const float* xp = &x[(((size_t)b * CIN + c0 + cS4) << 10) + l0 + lg4];
            float xv[4][4];
            #pragma unroll
            for (int cr = 0; cr < 4; cr++) {
                const float4 v = *(const float4*)(xp + ((size_t)cr << 10));
                xv[cr][0] = v.x; xv[cr][1] = v.y; xv[cr][2] = v.z; xv[cr][3] = v.w;
            }
            #pragma unroll
            for (int r = 0; r < 4; r++) {
                const int l = lg4 + r;
                const int col = (((cS4 >> 3) ^ (l & 3)) << 3) | (cS4 & 7);
                uint2v pk = { pkbf2(xv[0][r], xv[1][r]), pkbf2(xv[2][r], xv[3][r]) };
                *(uint2v*)&Xs[l][col] = pk;
            }
        }
        if (t < 192) {   // W tile: 96x32, fp32 -> bf16 packed, b128 writes
            const int o = t >> 1, cs = (t & 1) * 16;
            const float* wp = &w[(size_t)(o0 + o) * CIN + c0 + cs];
            const float4 w0 = *(const float4*)(wp);
            const float4 w1 = *(const float4*)(wp + 4);
            const float4 w2 = *(const float4*)(wp + 8);
            const float4 w3 = *(const float4*)(wp + 12);
            uint4v pa = { pkbf2(w0.x, w0.y), pkbf2(w0.z, w0.w),
                          pkbf2(w1.x, w1.y), pkbf2(w1.z, w1.w) };
            uint4v pb = { pkbf2(w2.x, w2.y), pkbf2(w2.z, w2.w),
                          pkbf2(w3.x, w3.y), pkbf2(w3.z, w3.w) };
            *(uint4v*)&Wt[o][cs]     = pa;
            *(uint4v*)&Wt[o][cs + 8] = pb;
        }
        __syncthreads();

        const int gsw = (quad ^ (n & 3)) * 8;
        short8 af[2];
        af[0] = *(const short8*)&Xs[wv * 32 + n][gsw];
        af[1] = *(const short8*)&Xs[wv * 32 + 16 + n][gsw];
        #pragma unroll
        for (int nf = 0; nf < 6; nf++) {
            const short8 bf = *(const short8*)&Wt[nf * 16 + n][quad * 8];
            #pragma unroll
            for (int a = 0; a < 2; a++)
                acc[a][nf] = __builtin_amdgcn_mfma_f32_16x16x32_bf16(af[a], bf, acc[a][nf], 0, 0, 0);
        }
        __syncthreads();
    }

    #pragma unroll
    for (int a = 0; a < 2; a++)
        #pragma unroll
        for (int reg = 0; reg < 4; reg++) {
            const size_t l = l0 + wv * 32 + a * 16 + quad * 4 + reg;
            short* row = qkvT + (((size_t)b << 10) + l) * 768 + o0 + n;
            #pragma unroll
            for (int nf = 0; nf < 6; nf++)
                row[nf * 16] = f2bf_hu(acc[a][nf][reg] + bias_r[nf]);
        }
}

// ---------------------------------------------------------------------------
// Proj GEMM (r12 validated, unchanged).
// ---------------------------------------------------------------------------
__global__ __launch_bounds__(256) void proj_gemm(
    const short* __restrict__ aT, const float* __restrict__ w,
    const float* __restrict__ bias, const float* __restrict__ resid,
    float* __restrict__ out)
{
    __shared__ short Xs[64][40];
    __shared__ short Wt[64][40];
    const int t = threadIdx.x, lane = t & 63, wv = t >> 6;
    const int n = lane & 15, quad = lane >> 4;
    const int b = blockIdx.z, o0 = blockIdx.y * 64, l0 = blockIdx.x * 64;

    float bias_r[4];
    #pragma unroll
    for (int reg = 0; reg < 4; reg++) bias_r[reg] = bias[o0 + wv * 16 + quad * 4 + reg];

    f32x4 acc[4];
    #pragma unroll
    for (int nf = 0; nf < 4; nf++) acc[nf] = (f32x4){0.f, 0.f, 0.f, 0.f};

    for (int c0 = 0; c0 < CIN; c0 += 32) {
        {   // aT tile 64x32 bf16
            const int l = t >> 2, cs = (t & 3) * 8;
            *(uint4v*)&Xs[l][cs] =
                *(const uint4v*)&aT[(((size_t)b << 10) + l0 + l) * CIN + c0 + cs];
        }
        {   // W tile 64x32, 8 floats per thread
            const int o = t >> 2, cs = (t & 3) * 8;
            const float* wp = &w[(size_t)(o0 + o) * CIN + c0 + cs];
            const float4 a4 = *(const float4*)(wp);
            const float4 b4 = *(const float4*)(wp + 4);
            uint4v pw = { pkbf2(a4.x, a4.y), pkbf2(a4.z, a4.w),
                          pkbf2(b4.x, b4.y), pkbf2(b4.z, b4.w) };
            *(uint4v*)&Wt[o][cs] = pw;
        }
        __syncthreads();

        const short8 af = *(const short8*)&Wt[wv * 16 + n][quad * 8];
        #pragma unroll
        for (int nf = 0; nf < 4; nf++) {
            const short8 bf = *(const short8*)&Xs[nf * 16 + n][quad * 8];
            acc[nf] = __builtin_amdgcn_mfma_f32_16x16x32_bf16(af, bf, acc[nf], 0, 0, 0);
        }
        __syncthreads();
    }

    #pragma unroll
    for (int reg = 0; reg < 4; reg++) {
        const int o = o0 + wv * 16 + quad * 4 + reg;
        #pragma unroll
        for (int nf = 0; nf < 4; nf++) {
            const size_t off = (((size_t)b * CIN + o) << 10) + l0 + nf * 16 + n;
            out[off] = acc[nf][reg] + bias_r[reg] + resid[off];
        }
    }
}

// ---------------------------------------------------------------------------
// Flash attention (r12 validated, byte-identical): Q-tile 128, 2 m-frags/wave,
// K direct from global, V double-buffered in LDS, register ones-column,
// exp2 intrinsic, bumped pointers, Ss stride 88, XCD swizzle. Grid 512.
// ---------------------------------------------------------------------------
__global__ __launch_bounds__(256) void attn_mfma(
    const short* __restrict__ qkvT, short* __restrict__ attnoT)
{
    __shared__ short Vt[2][32][80];                // col ^= ((dv>>2)&7)<<3
    __shared__ __align__(16) char umem[128 * 88 * 2];
    short (*Ss)[88] = (short(*)[88])umem;          // [i][j] bf16 P (wave-private rows)
    float (*OtT)[38] = (float(*)[38])umem;         // [i][dv] fp32 epilogue

    const int t = threadIdx.x, lane = t & 63, wv = t >> 6;
    const int n = lane & 15, quad = lane >> 4;
    const int id = blockIdx.x;
    const int bh = id & 63;                        // same-(b,h) -> same XCD
    const int b = bh >> 3, h = bh & 7;
    const int i0 = (id >> 6) * 128;

    const short* base = qkvT + ((size_t)b << 10) * 768;

    short8 qa[2];
    #pragma unroll
    for (int a = 0; a < 2; a++)
        qa[a] = *(const short8*)&base[(size_t)(i0 + wv * 32 + a * 16 + n) * 768
                                      + h * DH_ + quad * 8];

    short8 vf2;   // ones-column B-frag (denominator)
    {
        const short one = (n == 0) ? (short)0x3F80 : (short)0;
        #pragma unroll
        for (int u = 0; u < 8; u++) vf2[u] = one;
    }

    f32x4 o_acc[2][3];
    #pragma unroll
    for (int a = 0; a < 2; a++)
        #pragma unroll
        for (int nf = 0; nf < 3; nf++) o_acc[a][nf] = (f32x4){0.f, 0.f, 0.f, 0.f};

    const float K1 = 0.25503510f;    // (1/sqrt(32)) * log2(e)
    const float K2 = 11.54156036f;   // 8 * log2(e)
    const int TSTRIDE = 64 * 768;    // shorts per j-tile

    const short* kp0 = base + 256 + h * DH_ + (size_t)n * 768 + quad * 8;
    const short* kp1 = kp0 + 16 * 768;
    const short* kp2 = kp0 + 32 * 768;
    const short* kp3 = kp0 + 48 * 768;
    const int jS = t >> 3, dsS = (t & 7) * 4;
    const short* vp0 = base + 512 + h * DH_ + (size_t)jS * 768 + dsS;
    const short* vp1 = vp0 + 32 * 768;

    const int vmsk = ((dsS >> 2) & 7) << 3;
    const int vwo0 = dsS * 80 + (jS ^ vmsk);
    const int vwo1 = dsS * 80 + ((jS + 32) ^ vmsk);
    short* const vtb0 = &Vt[0][0][0];
    short* const vtb1 = &Vt[1][0][0];
    short* const ssw  = &Ss[wv * 32 + n][quad * 4];        // + a*16*88 + f*16
    const short* const ssr = &Ss[wv * 32 + n][quad * 8];   // + a*16*88 + kk*32
    int vro[2][2];
    #pragma unroll
    for (int nf = 0; nf < 2; nf++) {
        const int dv = nf * 16 + n;
        const int msk = ((dv >> 2) & 7) << 3;
        #pragma unroll
        for (int kk = 0; kk < 2; kk++)
            vro[kk][nf] = dv * 80 + ((kk * 32 + quad * 8) ^ msk);
    }

    short8 kfA[4], kfB[4];

    auto stageV = [&](short* vtb) {
        const short4v a = *(const short4v*)vp0; vp0 += TSTRIDE;
        const short4v c = *(const short4v*)vp1; vp1 += TSTRIDE;
        #pragma unroll
        for (int u = 0; u < 4; u++) {
            vtb[vwo0 + u * 80] = a[u];
            vtb[vwo1 + u * 80] = c[u];
        }
    };
    auto loadK = [&](short8* kf) {
        kf[0] = *(const short8*)kp0; kp0 += TSTRIDE;
        kf[1] = *(const short8*)kp1; kp1 += TSTRIDE;
        kf[2] = *(const short8*)kp2; kp2 += TSTRIDE;
        kf[3] = *(const short8*)kp3; kp3 += TSTRIDE;
    };
    auto tile = [&](const short8* kf, const short* vtb) {
        #pragma unroll
        for (int f = 0; f < 4; f++) {
            #pragma unroll
            for (int a = 0; a < 2; a++) {
                f32x4 z = {0.f, 0.f, 0.f, 0.f};
                const f32x4 sv = __builtin_amdgcn_mfma_f32_16x16x32_bf16(kf[f], qa[a], z, 0, 0, 0);
                const float p0 = __builtin_amdgcn_exp2f(fmaf(sv[0], K1, -K2));
                const float p1 = __builtin_amdgcn_exp2f(fmaf(sv[1], K1, -K2));
                const float p2 = __builtin_amdgcn_exp2f(fmaf(sv[2], K1, -K2));
                const float p3 = __builtin_amdgcn_exp2f(fmaf(sv[3], K1, -K2));
                uint2v pk = { pkbf2(p0, p1), pkbf2(p2, p3) };
                *(uint2v*)(ssw + a * 16 * 88 + f * 16) = pk;
            }
        }
        // wave-private Ss rows: in-wave DS ordering, no barrier
        #pragma unroll
        for (int kk = 0; kk < 2; kk++) {
            short8 pf[2];
            #pragma unroll
            for (int a = 0; a < 2; a++)
                pf[a] = *(const short8*)(ssr + a * 16 * 88 + kk * 32);
            #pragma unroll
            for (int nf = 0; nf < 2; nf++) {
                const short8 vf = *(const short8*)(vtb + vro[kk][nf]);
                #pragma unroll
                for (int a = 0; a < 2; a++)
                    o_acc[a][nf] = __builtin_amdgcn_mfma_f32_16x16x32_bf16(pf[a], vf, o_acc[a][nf], 0, 0, 0);
            }
            #pragma unroll
            for (int a = 0; a < 2; a++)
                o_acc[a][2] = __builtin_amdgcn_mfma_f32_16x16x32_bf16(pf[a], vf2, o_acc[a][2], 0, 0, 0);
        }
    };

    stageV(vtb0);
    loadK(kfA);

    for (int itp = 0; itp < 8; itp++) {
        __syncthreads();
        stageV(vtb1);
        loadK(kfB);
        tile(kfA, vtb0);
        __syncthreads();
        if (itp < 7) { stageV(vtb0); loadK(kfA); }
        tile(kfB, vtb1);
    }

    __syncthreads();   // all PV reads of Ss done before OtT overwrites umem
    #pragma unroll
    for (int a = 0; a < 2; a++)
        #pragma unroll
        for (int r = 0; r < 4; r++) {
            const float lv  = __shfl(o_acc[a][2][r], lane & 48, 64);
            const float inv = 1.f / lv;
            const int il = wv * 32 + a * 16 + quad * 4 + r;
            OtT[il][n]      = o_acc[a][0][r] * inv;
            OtT[il][16 + n] = o_acc[a][1][r] * inv;
        }
    __syncthreads();
    short* ob = attnoT + (((size_t)b << 10) + i0) * CIN + h * DH_;
    #pragma unroll
    for (int r = 0; r < 4; r++) {
        const int idx = t + r * 256;
        const int l = idx >> 3, cs = (idx & 7) * 4;
        uint2v pv;
        pv.x = pkbf2(OtT[l][cs],     OtT[l][cs + 1]);
        pv.y = pkbf2(OtT[l][cs + 2], OtT[l][cs + 3]);
        *(uint2v*)&ob[(size_t)l * CIN + cs] = pv;
    }
}

// ---------------------------------------------------------------------------
extern "C" void kernel_launch(void* const* d_in, const int* in_sizes, int n_in,
                              void* d_out, int out_size, void* d_ws, size_t ws_size,
                              hipStream_t stream) {
    const float* x      = (const float*)d_in[0];
    const float* w_qkv  = (const float*)d_in[1];
    const float* b_qkv  = (const float*)d_in[2];
    const float* w_proj = (const float*)d_in[3];
    const float* b_proj = (const float*)d_in[4];
    float* out = (float*)d_out;

    short* qkvT   = (short*)d_ws;                          // 12 MB [b][l][768]
    short* attnoT = qkvT + (size_t)B_ * L_ * 768;          // 4 MB  [b][l][256]

    qkv_gemm<<<dim3(8, 8, B_), 256, 0, stream>>>(x, w_qkv, b_qkv, qkvT);
    attn_mfma<<<dim3(512), 256, 0, stream>>>(qkvT, attnoT);
    proj_gemm<<<dim3(16, 4, B_), 256, 0, stream>>>(attnoT, w_proj, b_proj, x, out);
}

// Round 15
// 118.688 us; speedup vs baseline: 1.0645x; 1.0012x over previous
//
#include <hip/hip_runtime.h>
#include <math.h>

#define B_   8
#define CIN  256
#define L_   1024
#define NH_  8
#define DH_  32

typedef __attribute__((ext_vector_type(8))) short short8;
typedef __attribute__((ext_vector_type(4))) short short4v;
typedef __attribute__((ext_vector_type(4))) float f32x4;
typedef __attribute__((ext_vector_type(4))) unsigned int uint4v;
typedef __attribute__((ext_vector_type(2))) unsigned int uint2v;

__device__ inline short f2bf_hu(float f) {       // bf16 half-up, 2 ops
    union { float f; unsigned u; } v; v.f = f;
    return (short)((v.u + 0x8000u) >> 16);
}
// pack bf16(a) | bf16(b)<<16 : 2 adds + 1 v_perm
__device__ inline unsigned pkbf2(float a, float b) {
    union { float f; unsigned u; } x, y; x.f = a; y.f = b;
    return __builtin_amdgcn_perm(y.u + 0x8000u, x.u + 0x8000u, 0x07060302u);
}

// ---------------------------------------------------------------------------
// QKV GEMM (r12 tile/grid: 64l x 128o, 768 blocks = 3/CU) with FIXED X
// staging: thread owns 2c x 4l, loads 2 float4, writes 4 packed b32 to the
// swizzled layout -> 2 lanes/bank (free) vs 8-way scalar b16 before.
// qkvT[b][l][o] = x[b][:,l]·w_qkv[o][:] + bias[o], bf16, [l][768] layout.
// ---------------------------------------------------------------------------
__global__ __launch_bounds__(256) void qkv_gemm(
    const float* __restrict__ x, const float* __restrict__ w,
    const float* __restrict__ bias, short* __restrict__ qkvT)
{
    __shared__ short Xs[64][40];
    __shared__ short Wt[128][40];
    const int t = threadIdx.x, lane = t & 63, wv = t >> 6;
    const int n = lane & 15, quad = lane >> 4;
    const int b = blockIdx.z, o0 = blockIdx.y * 128, l0 = blockIdx.x * 64;

    float bias_r[8];
    #pragma unroll
    for (int nf = 0; nf < 8; nf++) bias_r[nf] = bias[o0 + nf * 16 + n];

    f32x4 acc[8];
    #pragma unroll
    for (int nf = 0; nf < 8; nf++) acc[nf] = (f32x4){0.f, 0.f, 0.f, 0.f};

    const int c2 = (t & 15) * 2;     // c base (0..30), 2 rows
    const int l4 = (t >> 4) * 4;     // l base (0..60), 4 cols

    for (int c0 = 0; c0 < CIN; c0 += 32) {
        {   // X stage: 2c x 4l register transpose, 4 packed b32 writes
            const float* xp = &x[(((size_t)b * CIN + c0 + c2) << 10) + l0 + l4];
            const float4 v0 = *(const float4*)xp;
            const float4 v1 = *(const float4*)(xp + 1024);
            const float a0[4] = {v0.x, v0.y, v0.z, v0.w};
            const float a1[4] = {v1.x, v1.y, v1.z, v1.w};
            #pragma unroll
            for (int r = 0; r < 4; r++) {
                const int l = l4 + r;
                const int col = (((c2 >> 3) ^ (l & 3)) << 3) | (c2 & 7);
                *(unsigned*)&Xs[l][col] = pkbf2(a0[r], a1[r]);
            }
        }
        {   // W tile: 128x32, fp32 -> bf16 packed, b128 writes (r12)
            const int o = t >> 1, cs = (t & 1) * 16;
            const float* wp = &w[(size_t)(o0 + o) * CIN + c0 + cs];
            const float4 w0 = *(const float4*)(wp);
            const float4 w1 = *(const float4*)(wp + 4);
            const float4 w2 = *(const float4*)(wp + 8);
            const float4 w3 = *(const float4*)(wp + 12);
            uint4v pa = { pkbf2(w0.x, w0.y), pkbf2(w0.z, w0.w),
                          pkbf2(w1.x, w1.y), pkbf2(w1.z, w1.w) };
            uint4v pb = { pkbf2(w2.x, w2.y), pkbf2(w2.z, w2.w),
                          pkbf2(w3.x, w3.y), pkbf2(w3.z, w3.w) };
            *(uint4v*)&Wt[o][cs]     = pa;
            *(uint4v*)&Wt[o][cs + 8] = pb;
        }
        __syncthreads();

        const int arow = wv * 16 + n;
        const short8 af = *(const short8*)&Xs[arow][(quad ^ (arow & 3)) * 8];
        #pragma unroll
        for (int nf = 0; nf < 8; nf++) {
            const short8 bf = *(const short8*)&Wt[nf * 16 + n][quad * 8];
            acc[nf] = __builtin_amdgcn_mfma_f32_16x16x32_bf16(af, bf, acc[nf], 0, 0, 0);
        }
        __syncthreads();
    }

    #pragma unroll
    for (int reg = 0; reg < 4; reg++) {
        const size_t l = l0 + wv * 16 + quad * 4 + reg;
        short* row = qkvT + (((size_t)b << 10) + l) * 768 + o0 + n;
        #pragma unroll
        for (int nf = 0; nf < 8; nf++)
            row[nf * 16] = f2bf_hu(acc[nf][reg] + bias_r[nf]);
    }
}

// ---------------------------------------------------------------------------
// Proj GEMM (r12 validated, unchanged).
// ---------------------------------------------------------------------------
__global__ __launch_bounds__(256) void proj_gemm(
    const short* __restrict__ aT, const float* __restrict__ w,
    const float* __restrict__ bias, const float* __restrict__ resid,
    float* __restrict__ out)
{
    __shared__ short Xs[64][40];
    __shared__ short Wt[64][40];
    const int t = threadIdx.x, lane = t & 63, wv = t >> 6;
    const int n = lane & 15, quad = lane >> 4;
    const int b = blockIdx.z, o0 = blockIdx.y * 64, l0 = blockIdx.x * 64;

    float bias_r[4];
    #pragma unroll
    for (int reg = 0; reg < 4; reg++) bias_r[reg] = bias[o0 + wv * 16 + quad * 4 + reg];

    f32x4 acc[4];
    #pragma unroll
    for (int nf = 0; nf < 4; nf++) acc[nf] = (f32x4){0.f, 0.f, 0.f, 0.f};

    for (int c0 = 0; c0 < CIN; c0 += 32) {
        {   // aT tile 64x32 bf16
            const int l = t >> 2, cs = (t & 3) * 8;
            *(uint4v*)&Xs[l][cs] =
                *(const uint4v*)&aT[(((size_t)b << 10) + l0 + l) * CIN + c0 + cs];
        }
        {   // W tile 64x32, 8 floats per thread
            const int o = t >> 2, cs = (t & 3) * 8;
            const float* wp = &w[(size_t)(o0 + o) * CIN + c0 + cs];
            const float4 a4 = *(const float4*)(wp);
            const float4 b4 = *(const float4*)(wp + 4);
            uint4v pw = { pkbf2(a4.x, a4.y), pkbf2(a4.z, a4.w),
                          pkbf2(b4.x, b4.y), pkbf2(b4.z, b4.w) };
            *(uint4v*)&Wt[o][cs] = pw;
        }
        __syncthreads();

        const short8 af = *(const short8*)&Wt[wv * 16 + n][quad * 8];
        #pragma unroll
        for (int nf = 0; nf < 4; nf++) {
            const short8 bf = *(const short8*)&Xs[nf * 16 + n][quad * 8];
            acc[nf] = __builtin_amdgcn_mfma_f32_16x16x32_bf16(af, bf, acc[nf], 0, 0, 0);
        }
        __syncthreads();
    }

    #pragma unroll
    for (int reg = 0; reg < 4; reg++) {
        const int o = o0 + wv * 16 + quad * 4 + reg;
        #pragma unroll
        for (int nf = 0; nf < 4; nf++) {
            const size_t off = (((size_t)b * CIN + o) << 10) + l0 + nf * 16 + n;
            out[off] = acc[nf][reg] + bias_r[reg] + resid[off];
        }
    }
}

// ---------------------------------------------------------------------------
// Flash attention (r12 validated, byte-identical): Q-tile 128, 2 m-frags/wave,
// K direct from global, V double-buffered in LDS, register ones-column,
// exp2 intrinsic, bumped pointers, Ss stride 88, XCD swizzle. Grid 512.
// ---------------------------------------------------------------------------
__global__ __launch_bounds__(256) void attn_mfma(
    const short* __restrict__ qkvT, short* __restrict__ attnoT)
{
    __shared__ short Vt[2][32][80];                // col ^= ((dv>>2)&7)<<3
    __shared__ __align__(16) char umem[128 * 88 * 2];
    short (*Ss)[88] = (short(*)[88])umem;          // [i][j] bf16 P (wave-private rows)
    float (*OtT)[38] = (float(*)[38])umem;         // [i][dv] fp32 epilogue

    const int t = threadIdx.x, lane = t & 63, wv = t >> 6;
    const int n = lane & 15, quad = lane >> 4;
    const int id = blockIdx.x;
    const int bh = id & 63;                        // same-(b,h) -> same XCD
    const int b = bh >> 3, h = bh & 7;
    const int i0 = (id >> 6) * 128;

    const short* base = qkvT + ((size_t)b << 10) * 768;

    short8 qa[2];
    #pragma unroll
    for (int a = 0; a < 2; a++)
        qa[a] = *(const short8*)&base[(size_t)(i0 + wv * 32 + a * 16 + n) * 768
                                      + h * DH_ + quad * 8];

    short8 vf2;   // ones-column B-frag (denominator)
    {
        const short one = (n == 0) ? (short)0x3F80 : (short)0;
        #pragma unroll
        for (int u = 0; u < 8; u++) vf2[u] = one;
    }

    f32x4 o_acc[2][3];
    #pragma unroll
    for (int a = 0; a < 2; a++)
        #pragma unroll
        for (int nf = 0; nf < 3; nf++) o_acc[a][nf] = (f32x4){0.f, 0.f, 0.f, 0.f};

    const float K1 = 0.25503510f;    // (1/sqrt(32)) * log2(e)
    const float K2 = 11.54156036f;   // 8 * log2(e)
    const int TSTRIDE = 64 * 768;    // shorts per j-tile

    const short* kp0 = base + 256 + h * DH_ + (size_t)n * 768 + quad * 8;
    const short* kp1 = kp0 + 16 * 768;
    const short* kp2 = kp0 + 32 * 768;
    const short* kp3 = kp0 + 48 * 768;
    const int jS = t >> 3, dsS = (t & 7) * 4;
    const short* vp0 = base + 512 + h * DH_ + (size_t)jS * 768 + dsS;
    const short* vp1 = vp0 + 32 * 768;

    const int vmsk = ((dsS >> 2) & 7) << 3;
    const int vwo0 = dsS * 80 + (jS ^ vmsk);
    const int vwo1 = dsS * 80 + ((jS + 32) ^ vmsk);
    short* const vtb0 = &Vt[0][0][0];
    short* const vtb1 = &Vt[1][0][0];
    short* const ssw  = &Ss[wv * 32 + n][quad * 4];        // + a*16*88 + f*16
    const short* const ssr = &Ss[wv * 32 + n][quad * 8];   // + a*16*88 + kk*32
    int vro[2][2];
    #pragma unroll
    for (int nf = 0; nf < 2; nf++) {
        const int dv = nf * 16 + n;
        const int msk = ((dv >> 2) & 7) << 3;
        #pragma unroll
        for (int kk = 0; kk < 2; kk++)
            vro[kk][nf] = dv * 80 + ((kk * 32 + quad * 8) ^ msk);
    }

    short8 kfA[4], kfB[4];

    auto stageV = [&](short* vtb) {
        const short4v a = *(const short4v*)vp0; vp0 += TSTRIDE;
        const short4v c = *(const short4v*)vp1; vp1 += TSTRIDE;
        #pragma unroll
        for (int u = 0; u < 4; u++) {
            vtb[vwo0 + u * 80] = a[u];
            vtb[vwo1 + u * 80] = c[u];
        }
    };
    auto loadK = [&](short8* kf) {
        kf[0] = *(const short8*)kp0; kp0 += TSTRIDE;
        kf[1] = *(const short8*)kp1; kp1 += TSTRIDE;
        kf[2] = *(const short8*)kp2; kp2 += TSTRIDE;
        kf[3] = *(const short8*)kp3; kp3 += TSTRIDE;
    };
    auto tile = [&](const short8* kf, const short* vtb) {
        #pragma unroll
        for (int f = 0; f < 4; f++) {
            #pragma unroll
            for (int a = 0; a < 2; a++) {
                f32x4 z = {0.f, 0.f, 0.f, 0.f};
                const f32x4 sv = __builtin_amdgcn_mfma_f32_16x16x32_bf16(kf[f], qa[a], z, 0, 0, 0);
                const float p0 = __builtin_amdgcn_exp2f(fmaf(sv[0], K1, -K2));
                const float p1 = __builtin_amdgcn_exp2f(fmaf(sv[1], K1, -K2));
                const float p2 = __builtin_amdgcn_exp2f(fmaf(sv[2], K1, -K2));
                const float p3 = __builtin_amdgcn_exp2f(fmaf(sv[3], K1, -K2));
                uint2v pk = { pkbf2(p0, p1), pkbf2(p2, p3) };
                *(uint2v*)(ssw + a * 16 * 88 + f * 16) = pk;
            }
        }
        // wave-private Ss rows: in-wave DS ordering, no barrier
        #pragma unroll
        for (int kk = 0; kk < 2; kk++) {
            short8 pf[2];
            #pragma unroll
            for (int a = 0; a < 2; a++)
                pf[a] = *(const short8*)(ssr + a * 16 * 88 + kk * 32);
            #pragma unroll
            for (int nf = 0; nf < 2; nf++) {
                const short8 vf = *(const short8*)(vtb + vro[kk][nf]);
                #pragma unroll
                for (int a = 0; a < 2; a++)
                    o_acc[a][nf] = __builtin_amdgcn_mfma_f32_16x16x32_bf16(pf[a], vf, o_acc[a][nf], 0, 0, 0);
            }
            #pragma unroll
            for (int a = 0; a < 2; a++)
                o_acc[a][2] = __builtin_amdgcn_mfma_f32_16x16x32_bf16(pf[a], vf2, o_acc[a][2], 0, 0, 0);
        }
    };

    stageV(vtb0);
    loadK(kfA);

    for (int itp = 0; itp < 8; itp++) {
        __syncthreads();
        stageV(vtb1);
        loadK(kfB);
        tile(kfA, vtb0);
        __syncthreads();
        if (itp < 7) { stageV(vtb0); loadK(kfA); }
        tile(kfB, vtb1);
    }

    __syncthreads();   // all PV reads of Ss done before OtT overwrites umem
    #pragma unroll
    for (int a = 0; a < 2; a++)
        #pragma unroll
        for (int r = 0; r < 4; r++) {
            const float lv  = __shfl(o_acc[a][2][r], lane & 48, 64);
            const float inv = 1.f / lv;
            const int il = wv * 32 + a * 16 + quad * 4 + r;
            OtT[il][n]      = o_acc[a][0][r] * inv;
            OtT[il][16 + n] = o_acc[a][1][r] * inv;
        }
    __syncthreads();
    short* ob = attnoT + (((size_t)b << 10) + i0) * CIN + h * DH_;
    #pragma unroll
    for (int r = 0; r < 4; r++) {
        const int idx = t + r * 256;
        const int l = idx >> 3, cs = (idx & 7) * 4;
        uint2v pv;
        pv.x = pkbf2(OtT[l][cs],     OtT[l][cs + 1]);
        pv.y = pkbf2(OtT[l][cs + 2], OtT[l][cs + 3]);
        *(uint2v*)&ob[(size_t)l * CIN + cs] = pv;
    }
}

// ---------------------------------------------------------------------------
extern "C" void kernel_launch(void* const* d_in, const int* in_sizes, int n_in,
                              void* d_out, int out_size, void* d_ws, size_t ws_size,
                              hipStream_t stream) {
    const float* x      = (const float*)d_in[0];
    const float* w_qkv  = (const float*)d_in[1];
    const float* b_qkv  = (const float*)d_in[2];
    const float* w_proj = (const float*)d_in[3];
    const float* b_proj = (const float*)d_in[4];
    float* out = (float*)d_out;

    short* qkvT   = (short*)d_ws;                          // 12 MB [b][l][768]
    short* attnoT = qkvT + (size_t)B_ * L_ * 768;          // 4 MB  [b][l][256]

    qkv_gemm<<<dim3(16, 6, B_), 256, 0, stream>>>(x, w_qkv, b_qkv, qkvT);
    attn_mfma<<<dim3(512), 256, 0, stream>>>(qkvT, attnoT);
    proj_gemm<<<dim3(16, 4, B_), 256, 0, stream>>>(attnoT, w_proj, b_proj, x, out);
}

// Round 16
// 114.903 us; speedup vs baseline: 1.0995x; 1.0329x over previous
//
#include <hip/hip_runtime.h>
#include <math.h>

#define B_   8
#define CIN  256
#define L_   1024
#define NH_  8
#define DH_  32

typedef __attribute__((ext_vector_type(8))) short short8;
typedef __attribute__((ext_vector_type(4))) short short4v;
typedef __attribute__((ext_vector_type(4))) float f32x4;
typedef __attribute__((ext_vector_type(4))) unsigned int uint4v;
typedef __attribute__((ext_vector_type(2))) unsigned int uint2v;

__device__ inline short f2bf_hu(float f) {       // bf16 half-up, 2 ops
    union { float f; unsigned u; } v; v.f = f;
    return (short)((v.u + 0x8000u) >> 16);
}
// pack bf16(a) | bf16(b)<<16 : 2 adds + 1 v_perm
__device__ inline unsigned pkbf2(float a, float b) {
    union { float f; unsigned u; } x, y; x.f = a; y.f = b;
    return __builtin_amdgcn_perm(y.u + 0x8000u, x.u + 0x8000u, 0x07060302u);
}

// ---------------------------------------------------------------------------
// QKV GEMM (r12-measured version, byte-identical).
// qkvT[b][l][o] = x[b][:,l]·w_qkv[o][:] + bias[o], bf16, [l][768] layout.
// Tile 64(l) x 128(o), grid 16x6x8 = 768 blocks = 3/CU exact.
// ---------------------------------------------------------------------------
__global__ __launch_bounds__(256) void qkv_gemm(
    const float* __restrict__ x, const float* __restrict__ w,
    const float* __restrict__ bias, short* __restrict__ qkvT)
{
    __shared__ short Xs[64][40];
    __shared__ short Wt[128][40];
    const int t = threadIdx.x, lane = t & 63, wv = t >> 6;
    const int n = lane & 15, quad = lane >> 4;
    const int b = blockIdx.z, o0 = blockIdx.y * 128, l0 = blockIdx.x * 64;

    float bias_r[8];
    #pragma unroll
    for (int nf = 0; nf < 8; nf++) bias_r[nf] = bias[o0 + nf * 16 + n];

    f32x4 acc[8];
    #pragma unroll
    for (int nf = 0; nf < 8; nf++) acc[nf] = (f32x4){0.f, 0.f, 0.f, 0.f};

    const int cS = t >> 3, lsS = (t & 7) * 8;       // X stage roles

    for (int c0 = 0; c0 < CIN; c0 += 32) {
        {   // X stage: 32c x 64l fp32, coalesced along l; swizzled transpose
            const float* xp = &x[(((size_t)b * CIN + c0 + cS) << 10) + l0 + lsS];
            const float4 xa = *(const float4*)xp;
            const float4 xb = *(const float4*)(xp + 4);
            const float vals[8] = {xa.x, xa.y, xa.z, xa.w, xb.x, xb.y, xb.z, xb.w};
            #pragma unroll
            for (int k = 0; k < 8; k++) {
                const int l = lsS + k;
                const int col = (((cS >> 3) ^ (l & 3)) << 3) | (cS & 7);
                Xs[l][col] = f2bf_hu(vals[k]);
            }
        }
        {   // W tile: 128x32, fp32 -> bf16 packed, b128 writes
            const int o = t >> 1, cs = (t & 1) * 16;
            const float* wp = &w[(size_t)(o0 + o) * CIN + c0 + cs];
            const float4 w0 = *(const float4*)(wp);
            const float4 w1 = *(const float4*)(wp + 4);
            const float4 w2 = *(const float4*)(wp + 8);
            const float4 w3 = *(const float4*)(wp + 12);
            uint4v pa = { pkbf2(w0.x, w0.y), pkbf2(w0.z, w0.w),
                          pkbf2(w1.x, w1.y), pkbf2(w1.z, w1.w) };
            uint4v pb = { pkbf2(w2.x, w2.y), pkbf2(w2.z, w2.w),
                          pkbf2(w3.x, w3.y), pkbf2(w3.z, w3.w) };
            *(uint4v*)&Wt[o][cs]     = pa;
            *(uint4v*)&Wt[o][cs + 8] = pb;
        }
        __syncthreads();

        const int arow = wv * 16 + n;
        const short8 af = *(const short8*)&Xs[arow][(quad ^ (arow & 3)) * 8];
        #pragma unroll
        for (int nf = 0; nf < 8; nf++) {
            const short8 bf = *(const short8*)&Wt[nf * 16 + n][quad * 8];
            acc[nf] = __builtin_amdgcn_mfma_f32_16x16x32_bf16(af, bf, acc[nf], 0, 0, 0);
        }
        __syncthreads();
    }

    #pragma unroll
    for (int reg = 0; reg < 4; reg++) {
        const size_t l = l0 + wv * 16 + quad * 4 + reg;
        short* row = qkvT + (((size_t)b << 10) + l) * 768 + o0 + n;
        #pragma unroll
        for (int nf = 0; nf < 8; nf++)
            row[nf * 16] = f2bf_hu(acc[nf][reg] + bias_r[nf]);
    }
}

// ---------------------------------------------------------------------------
// Proj GEMM with fused split-j combine (r10-validated staging): reads the
// two fp32 attention partials + denominators, normalizes, packs to bf16.
// out[b][o][l] = w[o][:]·attn[b][l][:] + bias[o] + resid[b][o][l]
// ---------------------------------------------------------------------------
__global__ __launch_bounds__(256) void proj_gemm(
    const float* __restrict__ partO, const float* __restrict__ partD,
    const float* __restrict__ w, const float* __restrict__ bias,
    const float* __restrict__ resid, float* __restrict__ out)
{
    __shared__ short Xs[64][40];
    __shared__ short Wt[64][40];
    const int t = threadIdx.x, lane = t & 63, wv = t >> 6;
    const int n = lane & 15, quad = lane >> 4;
    const int b = blockIdx.z, o0 = blockIdx.y * 64, l0 = blockIdx.x * 64;

    float bias_r[4];
    #pragma unroll
    for (int reg = 0; reg < 4; reg++) bias_r[reg] = bias[o0 + wv * 16 + quad * 4 + reg];

    f32x4 acc[4];
    #pragma unroll
    for (int nf = 0; nf < 4; nf++) acc[nf] = (f32x4){0.f, 0.f, 0.f, 0.f};

    for (int c0 = 0; c0 < CIN; c0 += 32) {
        {   // combine partials -> bf16 tile [64 l][32 c] (c0 spans one head)
            const int l = t >> 2, cs = (t & 3) * 8;
            const int h = c0 >> 5;
            const size_t li = ((size_t)b << 10) + l0 + l;
            const float* p0 = &partO[(0 * (size_t)B_ * L_ + li) * CIN + c0 + cs];
            const float* p1 = &partO[(1 * (size_t)B_ * L_ + li) * CIN + c0 + cs];
            const float d = partD[(0 * (size_t)B_ * L_ + li) * NH_ + h]
                          + partD[(1 * (size_t)B_ * L_ + li) * NH_ + h];
            const float inv = 1.f / d;
            const float4 a0 = *(const float4*)p0;
            const float4 a1 = *(const float4*)(p0 + 4);
            const float4 b0 = *(const float4*)p1;
            const float4 b1 = *(const float4*)(p1 + 4);
            uint4v pw = { pkbf2((a0.x + b0.x) * inv, (a0.y + b0.y) * inv),
                          pkbf2((a0.z + b0.z) * inv, (a0.w + b0.w) * inv),
                          pkbf2((a1.x + b1.x) * inv, (a1.y + b1.y) * inv),
                          pkbf2((a1.z + b1.z) * inv, (a1.w + b1.w) * inv) };
            *(uint4v*)&Xs[l][cs] = pw;
        }
        {   // W tile 64x32, 8 floats per thread
            const int o = t >> 2, cs = (t & 3) * 8;
            const float* wp = &w[(size_t)(o0 + o) * CIN + c0 + cs];
            const float4 a4 = *(const float4*)(wp);
            const float4 b4 = *(const float4*)(wp + 4);
            uint4v pw = { pkbf2(a4.x, a4.y), pkbf2(a4.z, a4.w),
                          pkbf2(b4.x, b4.y), pkbf2(b4.z, b4.w) };
            *(uint4v*)&Wt[o][cs] = pw;
        }
        __syncthreads();

        const short8 af = *(const short8*)&Wt[wv * 16 + n][quad * 8];
        #pragma unroll
        for (int nf = 0; nf < 4; nf++) {
            const short8 bf = *(const short8*)&Xs[nf * 16 + n][quad * 8];
            acc[nf] = __builtin_amdgcn_mfma_f32_16x16x32_bf16(af, bf, acc[nf], 0, 0, 0);
        }
        __syncthreads();
    }

    #pragma unroll
    for (int reg = 0; reg < 4; reg++) {
        const int o = o0 + wv * 16 + quad * 4 + reg;
        #pragma unroll
        for (int nf = 0; nf < 4; nf++) {
            const size_t off = (((size_t)b * CIN + o) << 10) + l0 + nf * 16 + n;
            out[off] = acc[nf][reg] + bias_r[reg] + resid[off];
        }
    }
}

// ---------------------------------------------------------------------------
// Flash attention: r12 core (Q-tile 128, 2 m-frags/wave, K direct, V LDS
// double-buffered, register ones-column, exp2 intrinsic, bumped pointers,
// Ss stride 88) + split-j x2 -> grid 1024 = 4 blocks/CU = 4 waves/SIMD x 2
// chains = 8 chains/SIMD. Epilogue: unnormalized fp32 partials + denom
// (no LDS transpose); proj combines. LDS 32 KB exactly.
// ---------------------------------------------------------------------------
__global__ __launch_bounds__(256) void attn_mfma(
    const short* __restrict__ qkvT, float* __restrict__ partO,
    float* __restrict__ partD)
{
    __shared__ short Vt[2][32][80];                // col ^= ((dv>>2)&7)<<3
    __shared__ __align__(16) short Ss[128][88];    // [i][j] bf16 P (wave-private rows)

    const int t = threadIdx.x, lane = t & 63, wv = t >> 6;
    const int n = lane & 15, quad = lane >> 4;
    const int id = blockIdx.x;
    const int bh = id & 63;                        // same-(b,h) -> same XCD
    const int b = bh >> 3, h = bh & 7;
    const int i0 = ((id >> 6) & 7) * 128;
    const int s  = id >> 9;                        // j-split 0/1

    const short* base = qkvT + ((size_t)b << 10) * 768;

    short8 qa[2];
    #pragma unroll
    for (int a = 0; a < 2; a++)
        qa[a] = *(const short8*)&base[(size_t)(i0 + wv * 32 + a * 16 + n) * 768
                                      + h * DH_ + quad * 8];

    short8 vf2;   // ones-column B-frag (denominator)
    {
        const short one = (n == 0) ? (short)0x3F80 : (short)0;
        #pragma unroll
        for (int u = 0; u < 8; u++) vf2[u] = one;
    }

    f32x4 o_acc[2][3];
    #pragma unroll
    for (int a = 0; a < 2; a++)
        #pragma unroll
        for (int nf = 0; nf < 3; nf++) o_acc[a][nf] = (f32x4){0.f, 0.f, 0.f, 0.f};

    const float K1 = 0.25503510f;    // (1/sqrt(32)) * log2(e)
    const float K2 = 11.54156036f;   // 8 * log2(e)
    const int TSTRIDE = 64 * 768;    // shorts per j-tile

    const size_t soff = (size_t)s * 8 * TSTRIDE;   // this block's j-half
    const short* kp0 = base + 256 + h * DH_ + (size_t)n * 768 + quad * 8 + soff;
    const short* kp1 = kp0 + 16 * 768;
    const short* kp2 = kp0 + 32 * 768;
    const short* kp3 = kp0 + 48 * 768;
    const int jS = t >> 3, dsS = (t & 7) * 4;
    const short* vp0 = base + 512 + h * DH_ + (size_t)jS * 768 + dsS + soff;
    const short* vp1 = vp0 + 32 * 768;

    const int vmsk = ((dsS >> 2) & 7) << 3;
    const int vwo0 = dsS * 80 + (jS ^ vmsk);
    const int vwo1 = dsS * 80 + ((jS + 32) ^ vmsk);
    short* const vtb0 = &Vt[0][0][0];
    short* const vtb1 = &Vt[1][0][0];
    short* const ssw  = &Ss[wv * 32 + n][quad * 4];        // + a*16*88 + f*16
    const short* const ssr = &Ss[wv * 32 + n][quad * 8];   // + a*16*88 + kk*32
    int vro[2][2];
    #pragma unroll
    for (int nf = 0; nf < 2; nf++) {
        const int dv = nf * 16 + n;
        const int msk = ((dv >> 2) & 7) << 3;
        #pragma unroll
        for (int kk = 0; kk < 2; kk++)
            vro[kk][nf] = dv * 80 + ((kk * 32 + quad * 8) ^ msk);
    }

    short8 kfA[4], kfB[4];

    auto stageV = [&](short* vtb) {
        const short4v a = *(const short4v*)vp0; vp0 += TSTRIDE;
        const short4v c = *(const short4v*)vp1; vp1 += TSTRIDE;
        #pragma unroll
        for (int u = 0; u < 4; u++) {
            vtb[vwo0 + u * 80] = a[u];
            vtb[vwo1 + u * 80] = c[u];
        }
    };
    auto loadK = [&](short8* kf) {
        kf[0] = *(const short8*)kp0; kp0 += TSTRIDE;
        kf[1] = *(const short8*)kp1; kp1 += TSTRIDE;
        kf[2] = *(const short8*)kp2; kp2 += TSTRIDE;
        kf[3] = *(const short8*)kp3; kp3 += TSTRIDE;
    };
    auto tile = [&](const short8* kf, const short* vtb) {
        #pragma unroll
        for (int f = 0; f < 4; f++) {
            #pragma unroll
            for (int a = 0; a < 2; a++) {
                f32x4 z = {0.f, 0.f, 0.f, 0.f};
                const f32x4 sv = __builtin_amdgcn_mfma_f32_16x16x32_bf16(kf[f], qa[a], z, 0, 0, 0);
                const float p0 = __builtin_amdgcn_exp2f(fmaf(sv[0], K1, -K2));
                const float p1 = __builtin_amdgcn_exp2f(fmaf(sv[1], K1, -K2));
                const float p2 = __builtin_amdgcn_exp2f(fmaf(sv[2], K1, -K2));
                const float p3 = __builtin_amdgcn_exp2f(fmaf(sv[3], K1, -K2));
                uint2v pk = { pkbf2(p0, p1), pkbf2(p2, p3) };
                *(uint2v*)(ssw + a * 16 * 88 + f * 16) = pk;
            }
        }
        // wave-private Ss rows: in-wave DS ordering, no barrier
        #pragma unroll
        for (int kk = 0; kk < 2; kk++) {
            short8 pf[2];
            #pragma unroll
            for (int a = 0; a < 2; a++)
                pf[a] = *(const short8*)(ssr + a * 16 * 88 + kk * 32);
            #pragma unroll
            for (int nf = 0; nf < 2; nf++) {
                const short8 vf = *(const short8*)(vtb + vro[kk][nf]);
                #pragma unroll
                for (int a = 0; a < 2; a++)
                    o_acc[a][nf] = __builtin_amdgcn_mfma_f32_16x16x32_bf16(pf[a], vf, o_acc[a][nf], 0, 0, 0);
            }
            #pragma unroll
            for (int a = 0; a < 2; a++)
                o_acc[a][2] = __builtin_amdgcn_mfma_f32_16x16x32_bf16(pf[a], vf2, o_acc[a][2], 0, 0, 0);
        }
    };

    stageV(vtb0);
    loadK(kfA);

    for (int itp = 0; itp < 4; itp++) {     // 8 j-tiles (this block's half)
        __syncthreads();
        stageV(vtb1);
        loadK(kfB);
        tile(kfA, vtb0);
        __syncthreads();
        if (itp < 3) { stageV(vtb0); loadK(kfA); }
        tile(kfB, vtb1);
    }

    // ---- epilogue: direct fp32 partial stores (no LDS, no barriers) ----
    #pragma unroll
    for (int a = 0; a < 2; a++) {
        #pragma unroll
        for (int r = 0; r < 4; r++) {
            const int il = i0 + wv * 32 + a * 16 + quad * 4 + r;
            float* po = partO + (((size_t)s * B_ + b) * L_ + il) * CIN + h * DH_;
            po[n]      = o_acc[a][0][r];
            po[16 + n] = o_acc[a][1][r];
        }
    }
    if (n == 0) {
        #pragma unroll
        for (int a = 0; a < 2; a++)
            #pragma unroll
            for (int r = 0; r < 4; r++) {
                const int il = i0 + wv * 32 + a * 16 + quad * 4 + r;
                partD[(((size_t)s * B_ + b) * L_ + il) * NH_ + h] = o_acc[a][2][r];
            }
    }
}

// ---------------------------------------------------------------------------
extern "C" void kernel_launch(void* const* d_in, const int* in_sizes, int n_in,
                              void* d_out, int out_size, void* d_ws, size_t ws_size,
                              hipStream_t stream) {
    const float* x      = (const float*)d_in[0];
    const float* w_qkv  = (const float*)d_in[1];
    const float* b_qkv  = (const float*)d_in[2];
    const float* w_proj = (const float*)d_in[3];
    const float* b_proj = (const float*)d_in[4];
    float* out = (float*)d_out;

    short* qkvT  = (short*)d_ws;                              // 12 MB bf16 [b][l][768]
    float* partO = (float*)(qkvT + (size_t)B_ * L_ * 768);    // 16 MB fp32 [2][b][l][256]
    float* partD = partO + (size_t)2 * B_ * L_ * CIN;         // 0.5 MB fp32 [2][b][l][8]

    qkv_gemm<<<dim3(16, 6, B_), 256, 0, stream>>>(x, w_qkv, b_qkv, qkvT);
    attn_mfma<<<dim3(1024), 256, 0, stream>>>(qkvT, partO, partD);
    proj_gemm<<<dim3(16, 4, B_), 256, 0, stream>>>(partO, partD, w_proj, b_proj, x, out);
}

// Round 17
// 114.396 us; speedup vs baseline: 1.1044x; 1.0044x over previous
//
#include <hip/hip_runtime.h>
#include <math.h>

#define B_   8
#define CIN  256
#define L_   1024
#define NH_  8
#define DH_  32

typedef __attribute__((ext_vector_type(8))) short short8;
typedef __attribute__((ext_vector_type(4))) short short4v;
typedef __attribute__((ext_vector_type(4))) float f32x4;
typedef __attribute__((ext_vector_type(4))) unsigned int uint4v;
typedef __attribute__((ext_vector_type(2))) unsigned int uint2v;

__device__ inline short f2bf_hu(float f) {       // bf16 half-up, 2 ops
    union { float f; unsigned u; } v; v.f = f;
    return (short)((v.u + 0x8000u) >> 16);
}
__device__ inline float bf2f(short s) {          // bf16 -> fp32, 1 shift
    union { unsigned u; float f; } v; v.u = ((unsigned)(unsigned short)s) << 16;
    return v.f;
}
// pack bf16(a) | bf16(b)<<16 : 2 adds + 1 v_perm
__device__ inline unsigned pkbf2(float a, float b) {
    union { float f; unsigned u; } x, y; x.f = a; y.f = b;
    return __builtin_amdgcn_perm(y.u + 0x8000u, x.u + 0x8000u, 0x07060302u);
}

// ---------------------------------------------------------------------------
// QKV GEMM (r12-measured version, byte-identical).
// qkvT[b][l][o] = x[b][:,l]·w_qkv[o][:] + bias[o], bf16, [l][768] layout.
// Tile 64(l) x 128(o), grid 16x6x8 = 768 blocks = 3/CU exact.
// ---------------------------------------------------------------------------
__global__ __launch_bounds__(256) void qkv_gemm(
    const float* __restrict__ x, const float* __restrict__ w,
    const float* __restrict__ bias, short* __restrict__ qkvT)
{
    __shared__ short Xs[64][40];
    __shared__ short Wt[128][40];
    const int t = threadIdx.x, lane = t & 63, wv = t >> 6;
    const int n = lane & 15, quad = lane >> 4;
    const int b = blockIdx.z, o0 = blockIdx.y * 128, l0 = blockIdx.x * 64;

    float bias_r[8];
    #pragma unroll
    for (int nf = 0; nf < 8; nf++) bias_r[nf] = bias[o0 + nf * 16 + n];

    f32x4 acc[8];
    #pragma unroll
    for (int nf = 0; nf < 8; nf++) acc[nf] = (f32x4){0.f, 0.f, 0.f, 0.f};

    const int cS = t >> 3, lsS = (t & 7) * 8;       // X stage roles

    for (int c0 = 0; c0 < CIN; c0 += 32) {
        {   // X stage: 32c x 64l fp32, coalesced along l; swizzled transpose
            const float* xp = &x[(((size_t)b * CIN + c0 + cS) << 10) + l0 + lsS];
            const float4 xa = *(const float4*)xp;
            const float4 xb = *(const float4*)(xp + 4);
            const float vals[8] = {xa.x, xa.y, xa.z, xa.w, xb.x, xb.y, xb.z, xb.w};
            #pragma unroll
            for (int k = 0; k < 8; k++) {
                const int l = lsS + k;
                const int col = (((cS >> 3) ^ (l & 3)) << 3) | (cS & 7);
                Xs[l][col] = f2bf_hu(vals[k]);
            }
        }
        {   // W tile: 128x32, fp32 -> bf16 packed, b128 writes
            const int o = t >> 1, cs = (t & 1) * 16;
            const float* wp = &w[(size_t)(o0 + o) * CIN + c0 + cs];
            const float4 w0 = *(const float4*)(wp);
            const float4 w1 = *(const float4*)(wp + 4);
            const float4 w2 = *(const float4*)(wp + 8);
            const float4 w3 = *(const float4*)(wp + 12);
            uint4v pa = { pkbf2(w0.x, w0.y), pkbf2(w0.z, w0.w),
                          pkbf2(w1.x, w1.y), pkbf2(w1.z, w1.w) };
            uint4v pb = { pkbf2(w2.x, w2.y), pkbf2(w2.z, w2.w),
                          pkbf2(w3.x, w3.y), pkbf2(w3.z, w3.w) };
            *(uint4v*)&Wt[o][cs]     = pa;
            *(uint4v*)&Wt[o][cs + 8] = pb;
        }
        __syncthreads();

        const int arow = wv * 16 + n;
        const short8 af = *(const short8*)&Xs[arow][(quad ^ (arow & 3)) * 8];
        #pragma unroll
        for (int nf = 0; nf < 8; nf++) {
            const short8 bf = *(const short8*)&Wt[nf * 16 + n][quad * 8];
            acc[nf] = __builtin_amdgcn_mfma_f32_16x16x32_bf16(af, bf, acc[nf], 0, 0, 0);
        }
        __syncthreads();
    }

    #pragma unroll
    for (int reg = 0; reg < 4; reg++) {
        const size_t l = l0 + wv * 16 + quad * 4 + reg;
        short* row = qkvT + (((size_t)b << 10) + l) * 768 + o0 + n;
        #pragma unroll
        for (int nf = 0; nf < 8; nf++)
            row[nf * 16] = f2bf_hu(acc[nf][reg] + bias_r[nf]);
    }
}

// ---------------------------------------------------------------------------
// Proj GEMM with fused split-j combine, partials now bf16 (half traffic):
// staging reads two bf16 partials + fp32 denominators, normalizes, packs.
// out[b][o][l] = w[o][:]·attn[b][l][:] + bias[o] + resid[b][o][l]
// ---------------------------------------------------------------------------
__global__ __launch_bounds__(256) void proj_gemm(
    const short* __restrict__ partO, const float* __restrict__ partD,
    const float* __restrict__ w, const float* __restrict__ bias,
    const float* __restrict__ resid, float* __restrict__ out)
{
    __shared__ short Xs[64][40];
    __shared__ short Wt[64][40];
    const int t = threadIdx.x, lane = t & 63, wv = t >> 6;
    const int n = lane & 15, quad = lane >> 4;
    const int b = blockIdx.z, o0 = blockIdx.y * 64, l0 = blockIdx.x * 64;

    float bias_r[4];
    #pragma unroll
    for (int reg = 0; reg < 4; reg++) bias_r[reg] = bias[o0 + wv * 16 + quad * 4 + reg];

    f32x4 acc[4];
    #pragma unroll
    for (int nf = 0; nf < 4; nf++) acc[nf] = (f32x4){0.f, 0.f, 0.f, 0.f};

    for (int c0 = 0; c0 < CIN; c0 += 32) {
        {   // combine bf16 partials -> bf16 tile [64 l][32 c] (c0 = one head)
            const int l = t >> 2, cs = (t & 3) * 8;
            const int h = c0 >> 5;
            const size_t li = ((size_t)b << 10) + l0 + l;
            const short8 s0 = *(const short8*)&partO[(0 * (size_t)B_ * L_ + li) * CIN + c0 + cs];
            const short8 s1 = *(const short8*)&partO[(1 * (size_t)B_ * L_ + li) * CIN + c0 + cs];
            const float d = partD[(0 * (size_t)B_ * L_ + li) * NH_ + h]
                          + partD[(1 * (size_t)B_ * L_ + li) * NH_ + h];
            const float inv = 1.f / d;
            float v[8];
            #pragma unroll
            for (int e = 0; e < 8; e++) v[e] = (bf2f(s0[e]) + bf2f(s1[e])) * inv;
            uint4v pw = { pkbf2(v[0], v[1]), pkbf2(v[2], v[3]),
                          pkbf2(v[4], v[5]), pkbf2(v[6], v[7]) };
            *(uint4v*)&Xs[l][cs] = pw;
        }
        {   // W tile 64x32, 8 floats per thread
            const int o = t >> 2, cs = (t & 3) * 8;
            const float* wp = &w[(size_t)(o0 + o) * CIN + c0 + cs];
            const float4 a4 = *(const float4*)(wp);
            const float4 b4 = *(const float4*)(wp + 4);
            uint4v pw = { pkbf2(a4.x, a4.y), pkbf2(a4.z, a4.w),
                          pkbf2(b4.x, b4.y), pkbf2(b4.z, b4.w) };
            *(uint4v*)&Wt[o][cs] = pw;
        }
        __syncthreads();

        const short8 af = *(const short8*)&Wt[wv * 16 + n][quad * 8];
        #pragma unroll
        for (int nf = 0; nf < 4; nf++) {
            const short8 bf = *(const short8*)&Xs[nf * 16 + n][quad * 8];
            acc[nf] = __builtin_amdgcn_mfma_f32_16x16x32_bf16(af, bf, acc[nf], 0, 0, 0);
        }
        __syncthreads();
    }

    #pragma unroll
    for (int reg = 0; reg < 4; reg++) {
        const int o = o0 + wv * 16 + quad * 4 + reg;
        #pragma unroll
        for (int nf = 0; nf < 4; nf++) {
            const size_t off = (((size_t)b * CIN + o) << 10) + l0 + nf * 16 + n;
            out[off] = acc[nf][reg] + bias_r[reg] + resid[off];
        }
    }
}

// ---------------------------------------------------------------------------
// Flash attention (r16 core, unchanged except bf16 partial stores):
// Q-tile 128, 2 m-frags/wave, K direct, V LDS double-buffered, register
// ones-column, exp2 intrinsic, bumped pointers, Ss stride 88, XCD swizzle,
// split-j x2 -> grid 1024 = 4 blocks/CU. LDS 32 KB exactly.
// ---------------------------------------------------------------------------
__global__ __launch_bounds__(256) void attn_mfma(
    const short* __restrict__ qkvT, short* __restrict__ partO,
    float* __restrict__ partD)
{
    __shared__ short Vt[2][32][80];                // col ^= ((dv>>2)&7)<<3
    __shared__ __align__(16) short Ss[128][88];    // [i][j] bf16 P (wave-private rows)

    const int t = threadIdx.x, lane = t & 63, wv = t >> 6;
    const int n = lane & 15, quad = lane >> 4;
    const int id = blockIdx.x;
    const int bh = id & 63;                        // same-(b,h) -> same XCD
    const int b = bh >> 3, h = bh & 7;
    const int i0 = ((id >> 6) & 7) * 128;
    const int s  = id >> 9;                        // j-split 0/1

    const short* base = qkvT + ((size_t)b << 10) * 768;

    short8 qa[2];
    #pragma unroll
    for (int a = 0; a < 2; a++)
        qa[a] = *(const short8*)&base[(size_t)(i0 + wv * 32 + a * 16 + n) * 768
                                      + h * DH_ + quad * 8];

    short8 vf2;   // ones-column B-frag (denominator)
    {
        const short one = (n == 0) ? (short)0x3F80 : (short)0;
        #pragma unroll
        for (int u = 0; u < 8; u++) vf2[u] = one;
    }

    f32x4 o_acc[2][3];
    #pragma unroll
    for (int a = 0; a < 2; a++)
        #pragma unroll
        for (int nf = 0; nf < 3; nf++) o_acc[a][nf] = (f32x4){0.f, 0.f, 0.f, 0.f};

    const float K1 = 0.25503510f;    // (1/sqrt(32)) * log2(e)
    const float K2 = 11.54156036f;   // 8 * log2(e)
    const int TSTRIDE = 64 * 768;    // shorts per j-tile

    const size_t soff = (size_t)s * 8 * TSTRIDE;   // this block's j-half
    const short* kp0 = base + 256 + h * DH_ + (size_t)n * 768 + quad * 8 + soff;
    const short* kp1 = kp0 + 16 * 768;
    const short* kp2 = kp0 + 32 * 768;
    const short* kp3 = kp0 + 48 * 768;
    const int jS = t >> 3, dsS = (t & 7) * 4;
    const short* vp0 = base + 512 + h * DH_ + (size_t)jS * 768 + dsS + soff;
    const short* vp1 = vp0 + 32 * 768;

    const int vmsk = ((dsS >> 2) & 7) << 3;
    const int vwo0 = dsS * 80 + (jS ^ vmsk);
    const int vwo1 = dsS * 80 + ((jS + 32) ^ vmsk);
    short* const vtb0 = &Vt[0][0][0];
    short* const vtb1 = &Vt[1][0][0];
    short* const ssw  = &Ss[wv * 32 + n][quad * 4];        // + a*16*88 + f*16
    const short* const ssr = &Ss[wv * 32 + n][quad * 8];   // + a*16*88 + kk*32
    int vro[2][2];
    #pragma unroll
    for (int nf = 0; nf < 2; nf++) {
        const int dv = nf * 16 + n;
        const int msk = ((dv >> 2) & 7) << 3;
        #pragma unroll
        for (int kk = 0; kk < 2; kk++)
            vro[kk][nf] = dv * 80 + ((kk * 32 + quad * 8) ^ msk);
    }

    short8 kfA[4], kfB[4];

    auto stageV = [&](short* vtb) {
        const short4v a = *(const short4v*)vp0; vp0 += TSTRIDE;
        const short4v c = *(const short4v*)vp1; vp1 += TSTRIDE;
        #pragma unroll
        for (int u = 0; u < 4; u++) {
            vtb[vwo0 + u * 80] = a[u];
            vtb[vwo1 + u * 80] = c[u];
        }
    };
    auto loadK = [&](short8* kf) {
        kf[0] = *(const short8*)kp0; kp0 += TSTRIDE;
        kf[1] = *(const short8*)kp1; kp1 += TSTRIDE;
        kf[2] = *(const short8*)kp2; kp2 += TSTRIDE;
        kf[3] = *(const short8*)kp3; kp3 += TSTRIDE;
    };
    auto tile = [&](const short8* kf, const short* vtb) {
        #pragma unroll
        for (int f = 0; f < 4; f++) {
            #pragma unroll
            for (int a = 0; a < 2; a++) {
                f32x4 z = {0.f, 0.f, 0.f, 0.f};
                const f32x4 sv = __builtin_amdgcn_mfma_f32_16x16x32_bf16(kf[f], qa[a], z, 0, 0, 0);
                const float p0 = __builtin_amdgcn_exp2f(fmaf(sv[0], K1, -K2));
                const float p1 = __builtin_amdgcn_exp2f(fmaf(sv[1], K1, -K2));
                const float p2 = __builtin_amdgcn_exp2f(fmaf(sv[2], K1, -K2));
                const float p3 = __builtin_amdgcn_exp2f(fmaf(sv[3], K1, -K2));
                uint2v pk = { pkbf2(p0, p1), pkbf2(p2, p3) };
                *(uint2v*)(ssw + a * 16 * 88 + f * 16) = pk;
            }
        }
        // wave-private Ss rows: in-wave DS ordering, no barrier
        #pragma unroll
        for (int kk = 0; kk < 2; kk++) {
            short8 pf[2];
            #pragma unroll
            for (int a = 0; a < 2; a++)
                pf[a] = *(const short8*)(ssr + a * 16 * 88 + kk * 32);
            #pragma unroll
            for (int nf = 0; nf < 2; nf++) {
                const short8 vf = *(const short8*)(vtb + vro[kk][nf]);
                #pragma unroll
                for (int a = 0; a < 2; a++)
                    o_acc[a][nf] = __builtin_amdgcn_mfma_f32_16x16x32_bf16(pf[a], vf, o_acc[a][nf], 0, 0, 0);
            }
            #pragma unroll
            for (int a = 0; a < 2; a++)
                o_acc[a][2] = __builtin_amdgcn_mfma_f32_16x16x32_bf16(pf[a], vf2, o_acc[a][2], 0, 0, 0);
        }
    };

    stageV(vtb0);
    loadK(kfA);

    for (int itp = 0; itp < 4; itp++) {     // 8 j-tiles (this block's half)
        __syncthreads();
        stageV(vtb1);
        loadK(kfB);
        tile(kfA, vtb0);
        __syncthreads();
        if (itp < 3) { stageV(vtb0); loadK(kfA); }
        tile(kfB, vtb1);
    }

    // ---- epilogue: bf16 partial stores (half traffic), fp32 denominators ----
    #pragma unroll
    for (int a = 0; a < 2; a++) {
        #pragma unroll
        for (int r = 0; r < 4; r++) {
            const int il = i0 + wv * 32 + a * 16 + quad * 4 + r;
            short* po = partO + (((size_t)s * B_ + b) * L_ + il) * CIN + h * DH_;
            po[n]      = f2bf_hu(o_acc[a][0][r]);
            po[16 + n] = f2bf_hu(o_acc[a][1][r]);
        }
    }
    if (n == 0) {
        #pragma unroll
        for (int a = 0; a < 2; a++)
            #pragma unroll
            for (int r = 0; r < 4; r++) {
                const int il = i0 + wv * 32 + a * 16 + quad * 4 + r;
                partD[(((size_t)s * B_ + b) * L_ + il) * NH_ + h] = o_acc[a][2][r];
            }
    }
}

// ---------------------------------------------------------------------------
extern "C" void kernel_launch(void* const* d_in, const int* in_sizes, int n_in,
                              void* d_out, int out_size, void* d_ws, size_t ws_size,
                              hipStream_t stream) {
    const float* x      = (const float*)d_in[0];
    const float* w_qkv  = (const float*)d_in[1];
    const float* b_qkv  = (const float*)d_in[2];
    const float* w_proj = (const float*)d_in[3];
    const float* b_proj = (const float*)d_in[4];
    float* out = (float*)d_out;

    short* qkvT  = (short*)d_ws;                              // 12 MB bf16 [b][l][768]
    short* partO = qkvT + (size_t)B_ * L_ * 768;              // 8.4 MB bf16 [2][b][l][256]
    float* partD = (float*)(partO + (size_t)2 * B_ * L_ * CIN); // 0.5 MB fp32 [2][b][l][8]

    qkv_gemm<<<dim3(16, 6, B_), 256, 0, stream>>>(x, w_qkv, b_qkv, qkvT);
    attn_mfma<<<dim3(1024), 256, 0, stream>>>(qkvT, partO, partD);
    proj_gemm<<<dim3(16, 4, B_), 256, 0, stream>>>(partO, partD, w_proj, b_proj, x, out);
}